// Round 2
// baseline (122.215 us; speedup 1.0000x reference)
//
#include <hip/hip_runtime.h>

// N=8192, D=16 RBF transport loss — all-MFMA, no-LDS (R12 structure).
// P^T via operand-swapped MFMA; C/D layout == A-operand layout, so exp(P^T)
// feeds the second MFMA directly.
// R15: bias-in-operand — D padded 16->32, mfma_f32_16x16x32_f16, RBF bias
// (ci+cj) rides in K-slots 16..19 as [1,1,c_hi,c_lo]x[c_hi,c_lo,1,1]
// (hi/lo f16 split; bias MUST stay pre-exp — removing it overflows fp16).
// R16 = R15 + aux-kernel occupancy & launch-count pass:
//   - k_prep 32->128 blocks (thread-per-quarter-row, shfl_xor row-sum)
//   - k_reduce 64->128 blocks (thread-per-quarter-row, h4 loads)
//   - k_final launch removed: sentinel block (blockIdx.y==34) in pass2 spins
//     on a done-counter (accums[2]) and writes out. Every worker block of the
//     32x34 grid increments exactly once (early-return path included) ->
//     target 1088 exact, no deadlock; sentinel branch is PRE-hot-loop, not
//     the R11/R13 epilogue-tail shape that blew up VGPRs.
#define NPTS 8192
#define DIM  16
#define DPAD 32   // 16 real dims + 4 bias dims + 12 zeros

constexpr int BLK = 256;

#define REG_LAMBDA 0.01f
#define C1 1.2011224087864498f   // sqrt(log2e)      -> exp(-d2/2)
#define C2 0.6005612043932249f   // 0.5*sqrt(log2e)  -> exp(-d2/8)
#define DONE_TARGET (32 * 34)

typedef _Float16 h4 __attribute__((ext_vector_type(4)));
typedef _Float16 h8 __attribute__((ext_vector_type(8)));
typedef float    f4 __attribute__((ext_vector_type(4)));

#define MFMA16(a, b, c) __builtin_amdgcn_mfma_f32_16x16x16f16((a), (b), (c), 0, 0, 0)
#define MFMA32(a, b, c) __builtin_amdgcn_mfma_f32_16x16x32_f16((a), (b), (c), 0, 0, 0)

#if __has_builtin(__builtin_amdgcn_exp2f)
#define EXP2(x) __builtin_amdgcn_exp2f(x)
#else
#define EXP2(x) exp2f(x)
#endif

__device__ __forceinline__ float dot4(float4 a, float4 b) {
  return fmaf(a.x, b.x, fmaf(a.y, b.y, fmaf(a.z, b.z, a.w * b.w)));
}

__device__ __forceinline__ float block_sum(float v, float* wbuf) {
#pragma unroll
  for (int o = 32; o > 0; o >>= 1) v += __shfl_down(v, o, 64);
  const int lane = threadIdx.x & 63;
  const int wid  = threadIdx.x >> 6;
  __syncthreads();
  if (lane == 0) wbuf[wid] = v;
  __syncthreads();
  float s = 0.f;
  if (threadIdx.x == 0) {
#pragma unroll
    for (int w = 0; w < BLK / 64; ++w) s += wbuf[w];
  }
  return s;
}

// Prep: 4 padded fp16 X copies (A/B role x scale C1/C2) with bias dims from
// ROUNDED X; Lam re-tiled into 16x16 MFMA B-fragment order. Thread-per-
// quarter-row (128 blocks); row ||x||^2 via width-4 shfl_xor butterfly.
// Zeroes accums (ws is poisoned 0xAA before every call).
__global__ __launch_bounds__(BLK) void k_prep(
    const float4* __restrict__ Xv, const float4* __restrict__ Lv,
    _Float16* __restrict__ XA1, _Float16* __restrict__ XB1,
    _Float16* __restrict__ XA2, _Float16* __restrict__ XB2,
    _Float16* __restrict__ LamB, float* __restrict__ accums) {
  if (blockIdx.x == 0 && threadIdx.x < 4) accums[threadIdx.x] = 0.f;
  const int t = blockIdx.x * BLK + threadIdx.x;
  const int i = t >> 2, q = t & 3;

  const float4 v = Xv[(size_t)i * 4 + q];
  const h4 a = {(_Float16)(C1 * v.x), (_Float16)(C1 * v.y),
                (_Float16)(C1 * v.z), (_Float16)(C1 * v.w)};
  const h4 b = {(_Float16)(C2 * v.x), (_Float16)(C2 * v.y),
                (_Float16)(C2 * v.z), (_Float16)(C2 * v.w)};
  float sq1 = 0.f, sq2 = 0.f;
#pragma unroll
  for (int r = 0; r < 4; ++r) {
    const float fa = (float)a[r], fb = (float)b[r];
    sq1 = fmaf(fa, fa, sq1);
    sq2 = fmaf(fb, fb, sq2);
  }
  // width-4 butterfly: all 4 quarter-threads of row i get the full row sum
  sq1 += __shfl_xor(sq1, 1, 64); sq1 += __shfl_xor(sq1, 2, 64);
  sq2 += __shfl_xor(sq2, 1, 64); sq2 += __shfl_xor(sq2, 2, 64);

  const float c1 = -0.5f * sq1, c2 = -0.5f * sq2;
  const _Float16 c1h = (_Float16)c1;
  const _Float16 c1l = (_Float16)(c1 - (float)c1h);
  const _Float16 c2h = (_Float16)c2;
  const _Float16 c2l = (_Float16)(c2 - (float)c2h);
  const _Float16 one = (_Float16)1.f;
  const _Float16 zer = (_Float16)0.f;
  const h4 z4 = {zer, zer, zer, zer};
  const h4 padA1 = {one, one, c1h, c1l};
  const h4 padB1 = {c1h, c1l, one, one};
  const h4 padA2 = {one, one, c2h, c2l};
  const h4 padB2 = {c2h, c2l, one, one};

  h4* rA1 = (h4*)(XA1 + (size_t)i * DPAD);
  h4* rB1 = (h4*)(XB1 + (size_t)i * DPAD);
  h4* rA2 = (h4*)(XA2 + (size_t)i * DPAD);
  h4* rB2 = (h4*)(XB2 + (size_t)i * DPAD);
  rA1[q] = a; rB1[q] = a; rA2[q] = b; rB2[q] = b;
  // pad slots 4..7: thread q writes slot 4+q; only q==0 carries the bias block
  rA1[4 + q] = (q == 0) ? padA1 : z4;
  rB1[4 + q] = (q == 0) ? padB1 : z4;
  rA2[4 + q] = (q == 0) ? padA2 : z4;
  rB2[4 + q] = (q == 0) ? padB2 : z4;

  // LamB tile order: element (row j, col d) of tile j>>4 lands at
  // lane l = ((j&15)>>2)*16 + d, reg r = j&3  (B-fragment of 16x16x16 MFMA).
  _Float16* lb = LamB + (size_t)(i >> 4) * 256 + ((i >> 2) & 3) * 64 + (i & 3);
  const float4 l = Lv[(size_t)i * 4 + q];
  lb[(4 * q + 0) * 4] = (_Float16)l.x;
  lb[(4 * q + 1) * 4] = (_Float16)l.y;
  lb[(4 * q + 2) * 4] = (_Float16)l.z;
  lb[(4 * q + 3) * 4] = (_Float16)l.w;
}

// Pass 1: U = exp2(K=32 biased dot) @ Lam. 4 i-tiles per wave, 256 i per
// block, grid (32, jc). Partials stored fp16.
__global__ __launch_bounds__(BLK) void k_pass1(
    const _Float16* __restrict__ XA1, const _Float16* __restrict__ XB1,
    const _Float16* __restrict__ LamB, _Float16* __restrict__ Upart, int span) {
  const int lane = threadIdx.x & 63;
  const int w    = threadIdx.x >> 6;
  const int l16  = lane & 15;
  const int quad = lane >> 4;

  const int i0 = blockIdx.x * 256 + w * 64;   // tiles i0+16t, t=0..3
  h8 bxi[4];
#pragma unroll
  for (int t = 0; t < 4; ++t)
    bxi[t] = *(const h8*)(XB1 + (size_t)(i0 + 16 * t + l16) * DPAD + quad * 8);

  const f4 fz = {0.f, 0.f, 0.f, 0.f};
  f4 U[4] = {fz, fz, fz, fz};
  const int jbeg = blockIdx.y * span;
  const int jend = jbeg + span;
#pragma unroll 4
  for (int j0 = jbeg; j0 < jend; j0 += 16) {
    const h8 axj = *(const h8*)(XA1 + (size_t)(j0 + l16) * DPAD + quad * 8);
    const h4 bl  = *(const h4*)(LamB + (size_t)(j0 >> 4) * 256 + lane * 4);
#pragma unroll
    for (int t = 0; t < 4; ++t) {
      const f4 p = MFMA32(axj, bxi[t], fz);   // P^T tile t, bias in K-slots
      const auto lo = __builtin_amdgcn_cvt_pkrtz(EXP2(p[0]), EXP2(p[1]));
      const auto hi = __builtin_amdgcn_cvt_pkrtz(EXP2(p[2]), EXP2(p[3]));
      h4 ap;
      ap[0] = lo[0]; ap[1] = lo[1]; ap[2] = hi[0]; ap[3] = hi[1];
      U[t] = MFMA16(ap, bl, U[t]);
    }
  }

  _Float16* dst = Upart + ((size_t)blockIdx.y * NPTS + i0) * DIM;
#pragma unroll
  for (int t = 0; t < 4; ++t)
#pragma unroll
    for (int r = 0; r < 4; ++r)
      dst[(16 * t + quad * 4 + r) * DIM + l16] = (_Float16)U[t][r];
}

// Reduce fp16 partials -> diff = U - Y (fp16 Dh); reg = sum(Lam * U).
// Thread-per-quarter-row (128 blocks), h4 = 8B/lane loads.
__global__ __launch_bounds__(BLK) void k_reduce(
    const _Float16* __restrict__ Upart, const float4* __restrict__ Yv,
    const float4* __restrict__ Lv, _Float16* __restrict__ Dh,
    float* __restrict__ accums, int jc) {
  __shared__ float wred[BLK / 64];
  const int t = blockIdx.x * BLK + threadIdx.x;
  const int i = t >> 2, q = t & 3;
  float u0 = 0.f, u1 = 0.f, u2 = 0.f, u3 = 0.f;
  for (int c = 0; c < jc; ++c) {
    const h4 p = *(const h4*)(Upart + ((size_t)c * NPTS + i) * DIM + q * 4);
    u0 += (float)p[0]; u1 += (float)p[1];
    u2 += (float)p[2]; u3 += (float)p[3];
  }
  const float4 y = Yv[(size_t)i * 4 + q];
  const h4 d = {(_Float16)(u0 - y.x), (_Float16)(u1 - y.y),
                (_Float16)(u2 - y.z), (_Float16)(u3 - y.w)};
  *(h4*)(Dh + (size_t)i * DIM + q * 4) = d;
  const float4 uu = {u0, u1, u2, u3};
  const float regp = dot4(Lv[(size_t)i * 4 + q], uu);
  const float rtot = block_sum(regp, wred);
  if (threadIdx.x == 0) unsafeAtomicAdd(&accums[1], rtot);
}

// Pass 2, symmetric: wrapped-triangle block map, early-return inactive blocks
// (NO epilogue tail — see R11/R13 note above). k=0 weight 1, else 2;
// k==16 only bi<16. Bias rides in the K=32 MFMA operands.
// blockIdx.y==34 is the fused-final sentinel: spins until all 1088 worker
// blocks increment accums[2], then writes out.
__global__ __launch_bounds__(BLK) void k_pass2(
    const _Float16* __restrict__ XA2, const _Float16* __restrict__ XB2,
    const _Float16* __restrict__ Dh, float* __restrict__ accums,
    float* __restrict__ out) {
  int* done = (int*)(accums + 2);
  if (blockIdx.y == 34) {                       // sentinel: fused k_final
    if (blockIdx.x != 0 || threadIdx.x != 0) return;
    while (__hip_atomic_load(done, __ATOMIC_ACQUIRE, __HIP_MEMORY_SCOPE_AGENT)
           < DONE_TARGET)
      __builtin_amdgcn_s_sleep(2);
    const float a0 = __hip_atomic_load(accums + 0, __ATOMIC_RELAXED,
                                       __HIP_MEMORY_SCOPE_AGENT);
    const float a1 = __hip_atomic_load(accums + 1, __ATOMIC_RELAXED,
                                       __HIP_MEMORY_SCOPE_AGENT);
    out[0] = a0 + REG_LAMBDA * a1;
    return;
  }

  __shared__ float wred[BLK / 64];
  const int bi   = blockIdx.x;
  const int k    = blockIdx.y >> 1;
  const int half = blockIdx.y & 1;
  if (k == 16 && bi >= 16) {                    // block-uniform exit
    if (threadIdx.x == 0)
      __hip_atomic_fetch_add(done, 1, __ATOMIC_RELEASE, __HIP_MEMORY_SCOPE_AGENT);
    return;
  }
  const int bj = (bi + k) & 31;
  const float weight = (k == 0) ? 1.f : 2.f;

  const int lane = threadIdx.x & 63;
  const int w    = threadIdx.x >> 6;
  const int l16  = lane & 15;
  const int quad = lane >> 4;
  const f4 fz = {0.f, 0.f, 0.f, 0.f};

  const int i0 = bi * 256 + w * 64;
  h8 ax[4];
  h4 ad[4];
#pragma unroll
  for (int t = 0; t < 4; ++t) {
    ax[t] = *(const h8*)(XA2 + (size_t)(i0 + 16 * t + l16) * DPAD + quad * 8);
    ad[t] = *(const h4*)(Dh  + (size_t)(i0 + 16 * t + l16) * DIM + quad * 4);
  }

  float s = 0.f;
  const int jbeg = bj * 256 + half * 128;
  const int jend = jbeg + 128;
#pragma unroll 4
  for (int j0 = jbeg; j0 < jend; j0 += 16) {
    const h8 bx = *(const h8*)(XB2 + (size_t)(j0 + l16) * DPAD + quad * 8);
    const h4 bd = *(const h4*)(Dh  + (size_t)(j0 + l16) * DIM + quad * 4);
#pragma unroll
    for (int t = 0; t < 4; ++t) {
      const f4 dx = MFMA32(ax[t], bx, fz);
      const f4 dd = MFMA16(ad[t], bd, fz);
#pragma unroll
      for (int r = 0; r < 4; ++r) s = fmaf(EXP2(dx[r]), dd[r], s);
    }
  }

  const float stot = block_sum(s * weight, wred);
  if (threadIdx.x == 0) {
    unsafeAtomicAdd(&accums[0], stot);
    __hip_atomic_fetch_add(done, 1, __ATOMIC_RELEASE, __HIP_MEMORY_SCOPE_AGENT);
  }
}

extern "C" void kernel_launch(void* const* d_in, const int* in_sizes, int n_in,
                              void* d_out, int out_size, void* d_ws, size_t ws_size,
                              hipStream_t stream) {
  const float4* Xv = (const float4*)d_in[0];
  const float4* Yv = (const float4*)d_in[1];
  const float4* Lv = (const float4*)d_in[2];
  float* out = (float*)d_out;

  // ws layout (bytes): XA1 512K | XB1 512K | XA2 512K | XB2 512K |
  //                    LamB 256K | Dh 256K | accums 256B | Upart jc*256K (fp16)
  char* base = (char*)d_ws;
  _Float16* XA1  = (_Float16*)(base);
  _Float16* XB1  = (_Float16*)(base + 512 * 1024);
  _Float16* XA2  = (_Float16*)(base + 1024 * 1024);
  _Float16* XB2  = (_Float16*)(base + 1536 * 1024);
  _Float16* LamB = (_Float16*)(base + 2048 * 1024);
  _Float16* Dh   = (_Float16*)(base + 2304 * 1024);
  float*    accums = (float*)(base + 2560 * 1024);
  _Float16* Upart  = (_Float16*)(base + 2560 * 1024 + 256);
  const size_t fixed = 2560 * 1024 + 256;

  int jc = 32;
  while (jc > 1 && fixed + (size_t)jc * NPTS * DIM * 2 > ws_size) jc >>= 1;
  const int span1 = NPTS / jc;

  k_prep<<<NPTS * 4 / BLK, BLK, 0, stream>>>(Xv, Lv, XA1, XB1, XA2, XB2, LamB, accums);
  k_pass1<<<dim3(NPTS / 256, jc), BLK, 0, stream>>>(XA1, XB1, LamB, Upart, span1);
  k_reduce<<<NPTS * 4 / BLK, BLK, 0, stream>>>(Upart, Yv, Lv, Dh, accums, jc);
  k_pass2<<<dim3(32, 35), BLK, 0, stream>>>(XA2, XB2, Dh, accums, out);
}

// Round 3
// 110.096 us; speedup vs baseline: 1.1101x; 1.1101x over previous
//
#include <hip/hip_runtime.h>

// N=8192, D=16 RBF transport loss — all-MFMA, no-LDS (R12 structure).
// P^T via operand-swapped MFMA; C/D layout == A-operand layout, so exp(P^T)
// feeds the second MFMA directly.
// R15: bias-in-operand — D padded 16->32, mfma_f32_16x16x32_f16, RBF bias
// (ci+cj) rides in K-slots 16..19 as [1,1,c_hi,c_lo]x[c_hi,c_lo,1,1]
// (hi/lo f16 split; bias MUST stay pre-exp — removing it overflows fp16).
// R17 = R15 structure + R16's wide aux kernels, sentinel REVERTED:
//   - R16's fused-final sentinel + agent-scope release done-counter cost
//     +10.6 us (1088 release atomics => per-XCD L2 writebacks on gfx950).
//     k_final is a separate launch again; accums atomics stay relaxed
//     (unsafeAtomicAdd). Do NOT reintroduce ordered agent-scope atomics.
//   - k_prep/k_reduce stay at 128 blocks (thread-per-quarter-row).
// NOTE: do NOT fuse k_final into pass2 via epilogue tail either — the
// if(active){hot loop} + tail structure allocates 164 VGPRs and 10x the
// kernel (R11/R13 evidence).
#define NPTS 8192
#define DIM  16
#define DPAD 32   // 16 real dims + 4 bias dims + 12 zeros

constexpr int BLK = 256;

#define REG_LAMBDA 0.01f
#define C1 1.2011224087864498f   // sqrt(log2e)      -> exp(-d2/2)
#define C2 0.6005612043932249f   // 0.5*sqrt(log2e)  -> exp(-d2/8)

typedef _Float16 h4 __attribute__((ext_vector_type(4)));
typedef _Float16 h8 __attribute__((ext_vector_type(8)));
typedef float    f4 __attribute__((ext_vector_type(4)));

#define MFMA16(a, b, c) __builtin_amdgcn_mfma_f32_16x16x16f16((a), (b), (c), 0, 0, 0)
#define MFMA32(a, b, c) __builtin_amdgcn_mfma_f32_16x16x32_f16((a), (b), (c), 0, 0, 0)

#if __has_builtin(__builtin_amdgcn_exp2f)
#define EXP2(x) __builtin_amdgcn_exp2f(x)
#else
#define EXP2(x) exp2f(x)
#endif

__device__ __forceinline__ float dot4(float4 a, float4 b) {
  return fmaf(a.x, b.x, fmaf(a.y, b.y, fmaf(a.z, b.z, a.w * b.w)));
}

__device__ __forceinline__ float block_sum(float v, float* wbuf) {
#pragma unroll
  for (int o = 32; o > 0; o >>= 1) v += __shfl_down(v, o, 64);
  const int lane = threadIdx.x & 63;
  const int wid  = threadIdx.x >> 6;
  __syncthreads();
  if (lane == 0) wbuf[wid] = v;
  __syncthreads();
  float s = 0.f;
  if (threadIdx.x == 0) {
#pragma unroll
    for (int w = 0; w < BLK / 64; ++w) s += wbuf[w];
  }
  return s;
}

// Prep: 4 padded fp16 X copies (A/B role x scale C1/C2) with bias dims from
// ROUNDED X; Lam re-tiled into 16x16 MFMA B-fragment order. Thread-per-
// quarter-row (128 blocks); row ||x||^2 via width-4 shfl_xor butterfly.
// Zeroes accums (ws is poisoned 0xAA before every call).
__global__ __launch_bounds__(BLK) void k_prep(
    const float4* __restrict__ Xv, const float4* __restrict__ Lv,
    _Float16* __restrict__ XA1, _Float16* __restrict__ XB1,
    _Float16* __restrict__ XA2, _Float16* __restrict__ XB2,
    _Float16* __restrict__ LamB, float* __restrict__ accums) {
  if (blockIdx.x == 0 && threadIdx.x < 4) accums[threadIdx.x] = 0.f;
  const int t = blockIdx.x * BLK + threadIdx.x;
  const int i = t >> 2, q = t & 3;

  const float4 v = Xv[(size_t)i * 4 + q];
  const h4 a = {(_Float16)(C1 * v.x), (_Float16)(C1 * v.y),
                (_Float16)(C1 * v.z), (_Float16)(C1 * v.w)};
  const h4 b = {(_Float16)(C2 * v.x), (_Float16)(C2 * v.y),
                (_Float16)(C2 * v.z), (_Float16)(C2 * v.w)};
  float sq1 = 0.f, sq2 = 0.f;
#pragma unroll
  for (int r = 0; r < 4; ++r) {
    const float fa = (float)a[r], fb = (float)b[r];
    sq1 = fmaf(fa, fa, sq1);
    sq2 = fmaf(fb, fb, sq2);
  }
  // width-4 butterfly: all 4 quarter-threads of row i get the full row sum
  sq1 += __shfl_xor(sq1, 1, 64); sq1 += __shfl_xor(sq1, 2, 64);
  sq2 += __shfl_xor(sq2, 1, 64); sq2 += __shfl_xor(sq2, 2, 64);

  const float c1 = -0.5f * sq1, c2 = -0.5f * sq2;
  const _Float16 c1h = (_Float16)c1;
  const _Float16 c1l = (_Float16)(c1 - (float)c1h);
  const _Float16 c2h = (_Float16)c2;
  const _Float16 c2l = (_Float16)(c2 - (float)c2h);
  const _Float16 one = (_Float16)1.f;
  const _Float16 zer = (_Float16)0.f;
  const h4 z4 = {zer, zer, zer, zer};
  const h4 padA1 = {one, one, c1h, c1l};
  const h4 padB1 = {c1h, c1l, one, one};
  const h4 padA2 = {one, one, c2h, c2l};
  const h4 padB2 = {c2h, c2l, one, one};

  h4* rA1 = (h4*)(XA1 + (size_t)i * DPAD);
  h4* rB1 = (h4*)(XB1 + (size_t)i * DPAD);
  h4* rA2 = (h4*)(XA2 + (size_t)i * DPAD);
  h4* rB2 = (h4*)(XB2 + (size_t)i * DPAD);
  rA1[q] = a; rB1[q] = a; rA2[q] = b; rB2[q] = b;
  // pad slots 4..7: thread q writes slot 4+q; only q==0 carries the bias block
  rA1[4 + q] = (q == 0) ? padA1 : z4;
  rB1[4 + q] = (q == 0) ? padB1 : z4;
  rA2[4 + q] = (q == 0) ? padA2 : z4;
  rB2[4 + q] = (q == 0) ? padB2 : z4;

  // LamB tile order: element (row j, col d) of tile j>>4 lands at
  // lane l = ((j&15)>>2)*16 + d, reg r = j&3  (B-fragment of 16x16x16 MFMA).
  _Float16* lb = LamB + (size_t)(i >> 4) * 256 + ((i >> 2) & 3) * 64 + (i & 3);
  const float4 l = Lv[(size_t)i * 4 + q];
  lb[(4 * q + 0) * 4] = (_Float16)l.x;
  lb[(4 * q + 1) * 4] = (_Float16)l.y;
  lb[(4 * q + 2) * 4] = (_Float16)l.z;
  lb[(4 * q + 3) * 4] = (_Float16)l.w;
}

// Pass 1: U = exp2(K=32 biased dot) @ Lam. 4 i-tiles per wave, 256 i per
// block, grid (32, jc). Partials stored fp16.
__global__ __launch_bounds__(BLK) void k_pass1(
    const _Float16* __restrict__ XA1, const _Float16* __restrict__ XB1,
    const _Float16* __restrict__ LamB, _Float16* __restrict__ Upart, int span) {
  const int lane = threadIdx.x & 63;
  const int w    = threadIdx.x >> 6;
  const int l16  = lane & 15;
  const int quad = lane >> 4;

  const int i0 = blockIdx.x * 256 + w * 64;   // tiles i0+16t, t=0..3
  h8 bxi[4];
#pragma unroll
  for (int t = 0; t < 4; ++t)
    bxi[t] = *(const h8*)(XB1 + (size_t)(i0 + 16 * t + l16) * DPAD + quad * 8);

  const f4 fz = {0.f, 0.f, 0.f, 0.f};
  f4 U[4] = {fz, fz, fz, fz};
  const int jbeg = blockIdx.y * span;
  const int jend = jbeg + span;
#pragma unroll 4
  for (int j0 = jbeg; j0 < jend; j0 += 16) {
    const h8 axj = *(const h8*)(XA1 + (size_t)(j0 + l16) * DPAD + quad * 8);
    const h4 bl  = *(const h4*)(LamB + (size_t)(j0 >> 4) * 256 + lane * 4);
#pragma unroll
    for (int t = 0; t < 4; ++t) {
      const f4 p = MFMA32(axj, bxi[t], fz);   // P^T tile t, bias in K-slots
      const auto lo = __builtin_amdgcn_cvt_pkrtz(EXP2(p[0]), EXP2(p[1]));
      const auto hi = __builtin_amdgcn_cvt_pkrtz(EXP2(p[2]), EXP2(p[3]));
      h4 ap;
      ap[0] = lo[0]; ap[1] = lo[1]; ap[2] = hi[0]; ap[3] = hi[1];
      U[t] = MFMA16(ap, bl, U[t]);
    }
  }

  _Float16* dst = Upart + ((size_t)blockIdx.y * NPTS + i0) * DIM;
#pragma unroll
  for (int t = 0; t < 4; ++t)
#pragma unroll
    for (int r = 0; r < 4; ++r)
      dst[(16 * t + quad * 4 + r) * DIM + l16] = (_Float16)U[t][r];
}

// Reduce fp16 partials -> diff = U - Y (fp16 Dh); reg = sum(Lam * U).
// Thread-per-quarter-row (128 blocks), h4 = 8B/lane loads.
__global__ __launch_bounds__(BLK) void k_reduce(
    const _Float16* __restrict__ Upart, const float4* __restrict__ Yv,
    const float4* __restrict__ Lv, _Float16* __restrict__ Dh,
    float* __restrict__ accums, int jc) {
  __shared__ float wred[BLK / 64];
  const int t = blockIdx.x * BLK + threadIdx.x;
  const int i = t >> 2, q = t & 3;
  float u0 = 0.f, u1 = 0.f, u2 = 0.f, u3 = 0.f;
  for (int c = 0; c < jc; ++c) {
    const h4 p = *(const h4*)(Upart + ((size_t)c * NPTS + i) * DIM + q * 4);
    u0 += (float)p[0]; u1 += (float)p[1];
    u2 += (float)p[2]; u3 += (float)p[3];
  }
  const float4 y = Yv[(size_t)i * 4 + q];
  const h4 d = {(_Float16)(u0 - y.x), (_Float16)(u1 - y.y),
                (_Float16)(u2 - y.z), (_Float16)(u3 - y.w)};
  *(h4*)(Dh + (size_t)i * DIM + q * 4) = d;
  const float4 uu = {u0, u1, u2, u3};
  const float regp = dot4(Lv[(size_t)i * 4 + q], uu);
  const float rtot = block_sum(regp, wred);
  if (threadIdx.x == 0) unsafeAtomicAdd(&accums[1], rtot);
}

// Pass 2, symmetric: wrapped-triangle block map, early-return inactive blocks
// (NO epilogue tail — see R11/R13 note above). k=0 weight 1, else 2;
// k==16 only bi<16. Bias rides in the K=32 MFMA operands.
__global__ __launch_bounds__(BLK) void k_pass2(
    const _Float16* __restrict__ XA2, const _Float16* __restrict__ XB2,
    const _Float16* __restrict__ Dh, float* __restrict__ accums) {
  __shared__ float wred[BLK / 64];
  const int bi   = blockIdx.x;
  const int k    = blockIdx.y >> 1;
  const int half = blockIdx.y & 1;
  if (k == 16 && bi >= 16) return;   // block-uniform exit
  const int bj = (bi + k) & 31;
  const float weight = (k == 0) ? 1.f : 2.f;

  const int lane = threadIdx.x & 63;
  const int w    = threadIdx.x >> 6;
  const int l16  = lane & 15;
  const int quad = lane >> 4;
  const f4 fz = {0.f, 0.f, 0.f, 0.f};

  const int i0 = bi * 256 + w * 64;
  h8 ax[4];
  h4 ad[4];
#pragma unroll
  for (int t = 0; t < 4; ++t) {
    ax[t] = *(const h8*)(XA2 + (size_t)(i0 + 16 * t + l16) * DPAD + quad * 8);
    ad[t] = *(const h4*)(Dh  + (size_t)(i0 + 16 * t + l16) * DIM + quad * 4);
  }

  float s = 0.f;
  const int jbeg = bj * 256 + half * 128;
  const int jend = jbeg + 128;
#pragma unroll 4
  for (int j0 = jbeg; j0 < jend; j0 += 16) {
    const h8 bx = *(const h8*)(XB2 + (size_t)(j0 + l16) * DPAD + quad * 8);
    const h4 bd = *(const h4*)(Dh  + (size_t)(j0 + l16) * DIM + quad * 4);
#pragma unroll
    for (int t = 0; t < 4; ++t) {
      const f4 dx = MFMA32(ax[t], bx, fz);
      const f4 dd = MFMA16(ad[t], bd, fz);
#pragma unroll
      for (int r = 0; r < 4; ++r) s = fmaf(EXP2(dx[r]), dd[r], s);
    }
  }

  const float stot = block_sum(s * weight, wred);
  if (threadIdx.x == 0) unsafeAtomicAdd(&accums[0], stot);
}

__global__ void k_final(const float* __restrict__ accums, float* __restrict__ out) {
  out[0] = accums[0] + REG_LAMBDA * accums[1];
}

extern "C" void kernel_launch(void* const* d_in, const int* in_sizes, int n_in,
                              void* d_out, int out_size, void* d_ws, size_t ws_size,
                              hipStream_t stream) {
  const float4* Xv = (const float4*)d_in[0];
  const float4* Yv = (const float4*)d_in[1];
  const float4* Lv = (const float4*)d_in[2];
  float* out = (float*)d_out;

  // ws layout (bytes): XA1 512K | XB1 512K | XA2 512K | XB2 512K |
  //                    LamB 256K | Dh 256K | accums 256B | Upart jc*256K (fp16)
  char* base = (char*)d_ws;
  _Float16* XA1  = (_Float16*)(base);
  _Float16* XB1  = (_Float16*)(base + 512 * 1024);
  _Float16* XA2  = (_Float16*)(base + 1024 * 1024);
  _Float16* XB2  = (_Float16*)(base + 1536 * 1024);
  _Float16* LamB = (_Float16*)(base + 2048 * 1024);
  _Float16* Dh   = (_Float16*)(base + 2304 * 1024);
  float*    accums = (float*)(base + 2560 * 1024);
  _Float16* Upart  = (_Float16*)(base + 2560 * 1024 + 256);
  const size_t fixed = 2560 * 1024 + 256;

  int jc = 32;
  while (jc > 1 && fixed + (size_t)jc * NPTS * DIM * 2 > ws_size) jc >>= 1;
  const int span1 = NPTS / jc;

  k_prep<<<NPTS * 4 / BLK, BLK, 0, stream>>>(Xv, Lv, XA1, XB1, XA2, XB2, LamB, accums);
  k_pass1<<<dim3(NPTS / 256, jc), BLK, 0, stream>>>(XA1, XB1, LamB, Upart, span1);
  k_reduce<<<NPTS * 4 / BLK, BLK, 0, stream>>>(Upart, Yv, Lv, Dh, accums, jc);
  k_pass2<<<dim3(32, 34), BLK, 0, stream>>>(XA2, XB2, Dh, accums);
  k_final<<<1, 1, 0, stream>>>(accums, out);
}